// Round 8
// baseline (492.594 us; speedup 1.0000x reference)
//
#include <hip/hip_runtime.h>
#include <math.h>

#define N_NODES 50000
#define N_EDGES 800000
#define D 256

typedef unsigned short u16;
typedef __attribute__((ext_vector_type(8))) __bf16 bf16x8;
typedef __attribute__((ext_vector_type(4))) float f32x4;

// GEMM tile geometry: 256x128 tile, 512 threads (8 waves 4m x 2n), BK=32.
// Per-buffer LDS (u16 units): Ah[0,8192) Al[8192,16384) Bh[16384,20480) Bl[20480,24576)
#define BUF_U16 24576
#define NBUF 3

// ---------------------------------------------------------------- helpers
__device__ __forceinline__ void split_hi_lo(float v, u16& h, u16& l) {
    unsigned u = __float_as_uint(v);
    unsigned hh = (u + 0x7fff + ((u >> 16) & 1)) >> 16;   // RNE bf16
    float hf = __uint_as_float(hh << 16);
    float res = v - hf;
    unsigned ul = __float_as_uint(res);
    unsigned ll = (ul + 0x7fff + ((ul >> 16) & 1)) >> 16;
    h = (u16)hh; l = (u16)ll;
}

__device__ __forceinline__ float bflo(unsigned u) { return __uint_as_float(u << 16); }
__device__ __forceinline__ float bfhi(unsigned u) { return __uint_as_float(u & 0xffff0000u); }

__device__ __forceinline__ void gl_lds16(const void* g, void* l) {
    __builtin_amdgcn_global_load_lds(
        (const __attribute__((address_space(1))) void*)g,
        (__attribute__((address_space(3))) void*)l, 16, 0, 0);
}

// ---------------------------------------------------------------- utilities
__global__ void count_deg(const int* __restrict__ ei, int* __restrict__ cnt) {
    int e = blockIdx.x * blockDim.x + threadIdx.x;
    if (e < N_EDGES) atomicAdd(&cnt[ei[N_EDGES + e]], 1);
}

__global__ void scan1(const int* __restrict__ cnt, int* __restrict__ partial,
                      int* __restrict__ bsum) {
    __shared__ int s[1024];
    int t = threadIdx.x, b = blockIdx.x;
    int gid = b * 1024 + t;
    int v = (gid < N_NODES) ? cnt[gid] : 0;
    s[t] = v;
    __syncthreads();
    for (int off = 1; off < 1024; off <<= 1) {
        int u = (t >= off) ? s[t - off] : 0;
        __syncthreads();
        s[t] += u;
        __syncthreads();
    }
    partial[gid] = s[t];
    if (t == 1023) bsum[b] = s[1023];
}

__global__ void scan2(const int* __restrict__ bsum, int* __restrict__ boff, int nb) {
    int t = threadIdx.x;
    int orig = (t < nb) ? bsum[t] : 0;
    int v = orig;
    #pragma unroll
    for (int off = 1; off < 64; off <<= 1) {
        int u = __shfl_up(v, off, 64);
        if (t >= off) v += u;
    }
    boff[t] = v - orig;
}

__global__ void scan3(const int* __restrict__ partial, const int* __restrict__ boff,
                      int* __restrict__ rowptr, int* __restrict__ cursor) {
    int i = blockIdx.x * blockDim.x + threadIdx.x;
    if (i <= N_NODES) {
        int val = 0;
        if (i > 0) val = partial[i - 1] + boff[(i - 1) >> 10];
        rowptr[i] = val;
        if (i < N_NODES) cursor[i] = val;
    }
}

__global__ void fill_edges(const int* __restrict__ ei, int* __restrict__ cursor,
                           int* __restrict__ esrc) {
    int e = blockIdx.x * blockDim.x + threadIdx.x;
    if (e < N_EDGES) {
        int p = atomicAdd(&cursor[ei[N_EDGES + e]], 1);
        esrc[p] = ei[e];
    }
}

// ------------------------------------------- fused fp32 -> bf16 hi/lo split
// One launch covers x (NF elems) + 5 weight matrices (NW = 65536 = 1<<16
// elems each). Segment decode is shift/mask; per-element op identical to the
// old per-tensor split_bf16 (bitwise-identical outputs).
#define NF_CONST (N_NODES * D)                 // 12,800,000
__global__ void split_all(const float* __restrict__ x,  u16* __restrict__ xh,  u16* __restrict__ xl,
                          const float* __restrict__ w0, u16* __restrict__ w0h, u16* __restrict__ w0l,
                          const float* __restrict__ w1, u16* __restrict__ w1h, u16* __restrict__ w1l,
                          const float* __restrict__ w2, u16* __restrict__ w2h, u16* __restrict__ w2l,
                          const float* __restrict__ w3, u16* __restrict__ w3h, u16* __restrict__ w3l,
                          const float* __restrict__ w4, u16* __restrict__ w4h, u16* __restrict__ w4l) {
    int i = blockIdx.x * blockDim.x + threadIdx.x;
    const float* src; u16* dh; u16* dl; int k;
    if (i < NF_CONST) {
        src = x; dh = xh; dl = xl; k = i;
    } else {
        int r = i - NF_CONST;
        int j = r >> 16;                      // which weight matrix
        k = r & 65535;
        switch (j) {
            case 0: src = w0; dh = w0h; dl = w0l; break;
            case 1: src = w1; dh = w1h; dl = w1l; break;
            case 2: src = w2; dh = w2h; dl = w2l; break;
            case 3: src = w3; dh = w3h; dl = w3l; break;
            default: if (j > 4) return;
                    src = w4; dh = w4h; dl = w4l; break;
        }
    }
    u16 h, l; split_hi_lo(src[k], h, l);
    dh[k] = h; dl[k] = l;
}

// ---------------------------------------------------------------- aggregation
// Persistent grid-stride: 2048 blocks x 4 waves; each wave loops over nodes
// (node += 8192). Per-node math/order identical to the one-node-per-wave
// version (bitwise-identical output); steadier occupancy, no 12.5K-block
// dispatch churn. Lanes 0-31 even edges, 32-63 odd; 16B/lane/edge.
__global__ __launch_bounds__(256) void aggregate_bf16(const u16* __restrict__ in_hi,
        const int* __restrict__ rowptr, const int* __restrict__ esrc,
        u16* __restrict__ ohi, u16* __restrict__ olo) {
    int lane = threadIdx.x & 63;
    int half = lane >> 5;            // 0: even edges, 1: odd edges
    int sub = lane & 31;             // 16B chunk within the 512B row
    const u16* rowp = in_hi + sub * 8;
    int node0 = blockIdx.x * 4 + (threadIdx.x >> 6);
    int stride = gridDim.x * 4;

    for (int node = node0; node < N_NODES; node += stride) {
        int beg = rowptr[node], end = rowptr[node + 1];

        float a0 = 0.f, a1 = 0.f, a2 = 0.f, a3 = 0.f;
        float a4 = 0.f, a5 = 0.f, a6 = 0.f, a7 = 0.f;

#define ACC8(v) \
        a0 += bflo(v.x); a1 += bfhi(v.x); a2 += bflo(v.y); a3 += bfhi(v.y); \
        a4 += bflo(v.z); a5 += bfhi(v.z); a6 += bflo(v.w); a7 += bfhi(v.w);

        int j = beg;
        for (; j + 16 <= end; j += 16) {
            int i0 = esrc[j +  0 + half];
            int i1 = esrc[j +  2 + half];
            int i2 = esrc[j +  4 + half];
            int i3 = esrc[j +  6 + half];
            int i4 = esrc[j +  8 + half];
            int i5 = esrc[j + 10 + half];
            int i6 = esrc[j + 12 + half];
            int i7 = esrc[j + 14 + half];
            uint4 r0 = *(const uint4*)(rowp + (size_t)i0 * D);
            uint4 r1 = *(const uint4*)(rowp + (size_t)i1 * D);
            uint4 r2 = *(const uint4*)(rowp + (size_t)i2 * D);
            uint4 r3 = *(const uint4*)(rowp + (size_t)i3 * D);
            uint4 r4 = *(const uint4*)(rowp + (size_t)i4 * D);
            uint4 r5 = *(const uint4*)(rowp + (size_t)i5 * D);
            uint4 r6 = *(const uint4*)(rowp + (size_t)i6 * D);
            uint4 r7 = *(const uint4*)(rowp + (size_t)i7 * D);
            ACC8(r0); ACC8(r1); ACC8(r2); ACC8(r3);
            ACC8(r4); ACC8(r5); ACC8(r6); ACC8(r7);
        }
        for (; j + 8 <= end; j += 8) {
            int i0 = esrc[j + 0 + half];
            int i1 = esrc[j + 2 + half];
            int i2 = esrc[j + 4 + half];
            int i3 = esrc[j + 6 + half];
            uint4 r0 = *(const uint4*)(rowp + (size_t)i0 * D);
            uint4 r1 = *(const uint4*)(rowp + (size_t)i1 * D);
            uint4 r2 = *(const uint4*)(rowp + (size_t)i2 * D);
            uint4 r3 = *(const uint4*)(rowp + (size_t)i3 * D);
            ACC8(r0); ACC8(r1); ACC8(r2); ACC8(r3);
        }
        for (; j < end; j += 2) {
            int e = j + half;
            if (e < end) {
                uint4 r = *(const uint4*)(rowp + (size_t)esrc[e] * D);
                ACC8(r);
            }
        }
#undef ACC8

        // combine even-edge half (lanes 0-31) with odd-edge half (32-63)
        a0 += __shfl_xor(a0, 32, 64); a1 += __shfl_xor(a1, 32, 64);
        a2 += __shfl_xor(a2, 32, 64); a3 += __shfl_xor(a3, 32, 64);
        a4 += __shfl_xor(a4, 32, 64); a5 += __shfl_xor(a5, 32, 64);
        a6 += __shfl_xor(a6, 32, 64); a7 += __shfl_xor(a7, 32, 64);

        if (lane < 32) {
            float inv = 1.f / (float)max(end - beg, 1);
            float m[8] = { a0 * inv, a1 * inv, a2 * inv, a3 * inv,
                           a4 * inv, a5 * inv, a6 * inv, a7 * inv };
            u16 h[8], l[8];
            #pragma unroll
            for (int k = 0; k < 8; ++k) split_hi_lo(m[k], h[k], l[k]);
            size_t o = (size_t)node * D + lane * 8;
            *(uint4*)(ohi + o) = make_uint4(h[0] | (h[1] << 16), h[2] | (h[3] << 16),
                                            h[4] | (h[5] << 16), h[6] | (h[7] << 16));
            *(uint4*)(olo + o) = make_uint4(l[0] | (l[1] << 16), l[2] | (l[3] << 16),
                                            l[4] | (l[5] << 16), l[6] | (l[7] << 16));
        }
    }
}

// ---------------------------------------------------------------- MFMA GEMM
// C[m,n] = act( A1[m,:]@B1[n,:] + A2[m,:]@B2[n,:] + bias[n] ), all operands
// split into bf16 hi/lo pairs; 3-term MFMA (hh + hl + lh) ~= fp32 precision.
// Depth-3 pipeline (T3+T4): 256x128 tile, 512 threads, 3 x 48 KB LDS buffers.
// Per step s: wait vmcnt(6) -> barrier -> stage s+2 -> 48 MFMA.
// Epilogue: C tile staged in LDS (buffers dead) then 16B/lane coalesced stores.
__device__ __forceinline__ void stage256(u16* buf,
        const u16* __restrict__ Ah, const u16* __restrict__ Al,
        const u16* __restrict__ Bh, const u16* __restrict__ Bl,
        int ks, int m0, int n0, int t) {
    int tr = t >> 2;                          // 0..127
    int g  = (t & 3) ^ ((t >> 3) & 3);        // pre-swizzled k-chunk
    size_t boff = (size_t)(n0 + tr) * D + ks + g * 8;
    gl_lds16(Bh + boff, buf + 16384 + t * 8);
    gl_lds16(Bl + boff, buf + 20480 + t * 8);
    #pragma unroll
    for (int r = 0; r < 2; ++r) {
        int arow = m0 + r * 128 + tr; if (arow >= N_NODES) arow = N_NODES - 1;
        size_t aoff = (size_t)arow * D + ks + g * 8;
        gl_lds16(Ah + aoff, buf + r * 4096 + t * 8);
        gl_lds16(Al + aoff, buf + 8192 + r * 4096 + t * 8);
    }
}

__global__ __launch_bounds__(512, 1) void gemm_mfma(
        const u16* __restrict__ A1h, const u16* __restrict__ A1l,
        const u16* __restrict__ A2h, const u16* __restrict__ A2l,
        const u16* __restrict__ B1h, const u16* __restrict__ B1l,
        const u16* __restrict__ B2h, const u16* __restrict__ B2l,
        const float* __restrict__ bias, int K,
        u16* __restrict__ Chi, u16* __restrict__ Clo) {
    extern __shared__ u16 sh[];               // 3 x 24576 u16 = 144 KB
    const int t = threadIdx.x;
    const int lane = t & 63;
    const int w = t >> 6;                     // 0..7
    const int wm = (w >> 1) * 64, wn = (w & 1) * 64;

    // XCD pair-swizzle: 392 blocks = 196 m-tiles x 2 n-tiles; (m,0)/(m,1)
    // are 8 dispatch slots apart -> same XCD, A-tile shared through its L2.
    int bid = blockIdx.x;
    int m_idx, n_idx;
    if (bid < 384) {
        m_idx = (bid >> 4) * 8 + (bid & 7);
        n_idx = (bid >> 3) & 1;
    } else {
        int r = bid - 384;                    // tail: 4 m-values x 2 n
        m_idx = 192 + (r & 3);
        n_idx = r >> 2;
    }
    const int m0 = m_idx * 256, n0 = n_idx * 128;

    f32x4 acc[4][4] = {};

    const int lm = lane & 15;
    const int sw = ((lane >> 4) ^ ((lm >> 1) & 3)) * 8;
    const int nsteps = K >> 5;

    // prologue: stage steps 0 and 1 (k0=0,32 always < 256 -> operand set 1)
    stage256(sh,           A1h, A1l, B1h, B1l,  0, m0, n0, t);
    stage256(sh + BUF_U16, A1h, A1l, B1h, B1l, 32, m0, n0, t);

    int cur = 0;
    for (int s = 0; s < nsteps; ++s) {
        if (s + 1 < nsteps) {
            asm volatile("s_waitcnt vmcnt(6)" ::: "memory");
        } else {
            asm volatile("s_waitcnt vmcnt(0)" ::: "memory");
        }
        __builtin_amdgcn_s_barrier();
        __builtin_amdgcn_sched_barrier(0);

        if (s + 2 < nsteps) {
            int sb = cur + 2; if (sb >= NBUF) sb -= NBUF;
            int ksg = (s + 2) * 32;
            if (ksg < 256) stage256(sh + sb * BUF_U16, A1h, A1l, B1h, B1l, ksg,       m0, n0, t);
            else           stage256(sh + sb * BUF_U16, A2h, A2l, B2h, B2l, ksg - 256, m0, n0, t);
        }

        const u16* buf = sh + cur * BUF_U16;
        bf16x8 ah[4], al[4], bh[4], bl[4];
        #pragma unroll
        for (int i = 0; i < 4; ++i) {
            int offA = (wm + i * 16 + lm) * 32 + sw;
            ah[i] = *(const bf16x8*)(buf + offA);
            al[i] = *(const bf16x8*)(buf + 8192 + offA);
            int offB = (wn + i * 16 + lm) * 32 + sw;
            bh[i] = *(const bf16x8*)(buf + 16384 + offB);
            bl[i] = *(const bf16x8*)(buf + 20480 + offB);
        }
        __builtin_amdgcn_s_setprio(1);
        #pragma unroll
        for (int i = 0; i < 4; ++i) {
            #pragma unroll
            for (int j = 0; j < 4; ++j) {
                acc[i][j] = __builtin_amdgcn_mfma_f32_16x16x32_bf16(ah[i], bh[j], acc[i][j], 0, 0, 0);
                acc[i][j] = __builtin_amdgcn_mfma_f32_16x16x32_bf16(ah[i], bl[j], acc[i][j], 0, 0, 0);
                acc[i][j] = __builtin_amdgcn_mfma_f32_16x16x32_bf16(al[i], bh[j], acc[i][j], 0, 0, 0);
            }
        }
        __builtin_amdgcn_s_setprio(0);

        cur = (cur == NBUF - 1) ? 0 : cur + 1;
    }

    // ---- epilogue: stage C tile in LDS (hi at [0,32768), lo at [32768,65536))
    __syncthreads();
    const int q = lane >> 4;
    #pragma unroll
    for (int j = 0; j < 4; ++j) {
        int col = wn + j * 16 + lm;
        float bb = bias[n0 + col];
        #pragma unroll
        for (int i = 0; i < 4; ++i) {
            #pragma unroll
            for (int r = 0; r < 4; ++r) {
                int row = wm + i * 16 + q * 4 + r;
                float v = fmaxf(acc[i][j][r] + bb, 0.f);
                u16 h, l; split_hi_lo(v, h, l);
                sh[row * 128 + col] = h;
                sh[32768 + row * 128 + col] = l;
            }
        }
    }
    __syncthreads();
    // coalesced 16B/lane stores: 4096 chunks per plane (256 rows x 16 chunks)
    for (int c = t; c < 4096; c += 512) {
        int row = c >> 4;
        int off = (c & 15) * 8;
        int grow = m0 + row;
        if (grow < N_NODES) {
            size_t o = (size_t)grow * D + n0 + off;
            *(uint4*)(Chi + o) = *(const uint4*)(sh + row * 128 + off);
            *(uint4*)(Clo + o) = *(const uint4*)(sh + 32768 + row * 128 + off);
        }
    }
}

// ----------------------------------------------------- fused GEMM3 + MLP2
// h3 = relu(h2 @ Wm1^T + bm1) as a 128x256 tile (full N in one block, K=256,
// depth-3/vmcnt(6) schedule); tile staged in LDS at padded stride 260.
// Decoder: distributed-k, 16 lanes per row; Wm2 slice preloaded to regs;
// 4-deep shfl_xor reduce + in-lane softmax; lane kl==0 stores 32 B.
__device__ __forceinline__ void stage_mlp(u16* buf,
        const u16* __restrict__ Ah, const u16* __restrict__ Al,
        const u16* __restrict__ Bh, const u16* __restrict__ Bl,
        int ks, int m0, int t) {
    int tr = t >> 2;                          // A: 128 rows, 1 load/plane
    int g  = (t & 3) ^ ((t >> 3) & 3);
    int arow = m0 + tr; if (arow >= N_NODES) arow = N_NODES - 1;
    size_t aoff = (size_t)arow * D + ks + g * 8;
    gl_lds16(Ah + aoff, buf + t * 8);                 // [0,4096)
    gl_lds16(Al + aoff, buf + 4096 + t * 8);          // [4096,8192)
    #pragma unroll
    for (int r = 0; r < 2; ++r) {             // B: 256 rows, 2 rounds/plane
        int u = r * 512 + t;                  // lane-linear dest per round
        int brow = u >> 2;
        int gb = (u & 3) ^ ((u >> 3) & 3);
        size_t boff = (size_t)brow * D + ks + gb * 8;
        gl_lds16(Bh + boff, buf + 8192  + u * 8);     // [8192,16384)
        gl_lds16(Bl + boff, buf + 16384 + u * 8);     // [16384,24576)
    }
}

__global__ __launch_bounds__(512, 1) void gemm_mlp2(
        const u16* __restrict__ Ah, const u16* __restrict__ Al,
        const u16* __restrict__ Bh, const u16* __restrict__ Bl,
        const float* __restrict__ bm1, const float* __restrict__ Wm2,
        const float* __restrict__ bm2, float* __restrict__ out) {
    extern __shared__ u16 sh[];               // 144 KB
    const int t = threadIdx.x;
    const int lane = t & 63;
    const int w = t >> 6;                     // 8 waves: 2m x 4n
    const int wm = (w >> 2) * 64, wn = (w & 3) * 64;
    const int m0 = blockIdx.x * 128;

    f32x4 acc[4][4] = {};
    const int lm = lane & 15;
    const int sw = ((lane >> 4) ^ ((lm >> 1) & 3)) * 8;
    const int nsteps = 8;                     // K = 256

    stage_mlp(sh,           Ah, Al, Bh, Bl,  0, m0, t);
    stage_mlp(sh + BUF_U16, Ah, Al, Bh, Bl, 32, m0, t);

    int cur = 0;
    for (int s = 0; s < nsteps; ++s) {
        if (s + 1 < nsteps) {
            asm volatile("s_waitcnt vmcnt(6)" ::: "memory");
        } else {
            asm volatile("s_waitcnt vmcnt(0)" ::: "memory");
        }
        __builtin_amdgcn_s_barrier();
        __builtin_amdgcn_sched_barrier(0);

        if (s + 2 < nsteps) {
            int sb = cur + 2; if (sb >= NBUF) sb -= NBUF;
            stage_mlp(sh + sb * BUF_U16, Ah, Al, Bh, Bl, (s + 2) * 32, m0, t);
        }

        const u16* buf = sh + cur * BUF_U16;
        bf16x8 a_h[4], a_l[4], b_h[4], b_l[4];
        #pragma unroll
        for (int i = 0; i < 4; ++i) {
            int offA = (wm + i * 16 + lm) * 32 + sw;
            a_h[i] = *(const bf16x8*)(buf + offA);
            a_l[i] = *(const bf16x8*)(buf + 4096 + offA);
            int offB = (wn + i * 16 + lm) * 32 + sw;
            b_h[i] = *(const bf16x8*)(buf + 8192 + offB);
            b_l[i] = *(const bf16x8*)(buf + 16384 + offB);
        }
        __builtin_amdgcn_s_setprio(1);
        #pragma unroll
        for (int i = 0; i < 4; ++i) {
            #pragma unroll
            for (int j = 0; j < 4; ++j) {
                acc[i][j] = __builtin_amdgcn_mfma_f32_16x16x32_bf16(a_h[i], b_h[j], acc[i][j], 0, 0, 0);
                acc[i][j] = __builtin_amdgcn_mfma_f32_16x16x32_bf16(a_h[i], b_l[j], acc[i][j], 0, 0, 0);
                acc[i][j] = __builtin_amdgcn_mfma_f32_16x16x32_bf16(a_l[i], b_h[j], acc[i][j], 0, 0, 0);
            }
        }
        __builtin_amdgcn_s_setprio(0);

        cur = (cur == NBUF - 1) ? 0 : cur + 1;
    }

    // ---- stage h3 tile (128 x 260-padded fp32 = 133 KB) in LDS
    __syncthreads();
    float* h3s = (float*)sh;
    const int q = lane >> 4;
    #pragma unroll
    for (int j = 0; j < 4; ++j) {
        int col = wn + j * 16 + lm;
        float bb = bm1[col];
        #pragma unroll
        for (int i = 0; i < 4; ++i) {
            #pragma unroll
            for (int r = 0; r < 4; ++r) {
                int row = wm + i * 16 + q * 4 + r;
                h3s[row * 260 + col] = fmaxf(acc[i][j][r] + bb, 0.f);
            }
        }
    }
    __syncthreads();

    // ---- distributed-k decoder + softmax
    const int kl = lane & 15;                 // fixed k-window (16 floats)
    const int sr = lane >> 4;                 // sub-row 0..3

    float4 wreg[8][4];
    float b2v[8];
    #pragma unroll
    for (int o = 0; o < 8; ++o) {
        b2v[o] = bm2[o];
        #pragma unroll
        for (int c = 0; c < 4; ++c)
            wreg[o][c] = *(const float4*)(Wm2 + o * D + kl * 16 + c * 4);
    }

    #pragma unroll
    for (int p = 0; p < 4; ++p) {
        int row  = w * 16 + p * 4 + sr;
        int grow = m0 + row;
        const float* hrow = h3s + row * 260 + kl * 16;
        float4 h0 = *(const float4*)(hrow);
        float4 h1 = *(const float4*)(hrow + 4);
        float4 h2 = *(const float4*)(hrow + 8);
        float4 h3v = *(const float4*)(hrow + 12);
        float part[8];
        #pragma unroll
        for (int o = 0; o < 8; ++o) {
            float s;
            s  = h0.x * wreg[o][0].x + h0.y * wreg[o][0].y
               + h0.z * wreg[o][0].z + h0.w * wreg[o][0].w;
            s += h1.x * wreg[o][1].x + h1.y * wreg[o][1].y
               + h1.z * wreg[o][1].z + h1.w * wreg[o][1].w;
            s += h2.x * wreg[o][2].x + h2.y * wreg[o][2].y
               + h2.z * wreg[o][2].z + h2.w * wreg[o][2].w;
            s += h3v.x * wreg[o][3].x + h3v.y * wreg[o][3].y
               + h3v.z * wreg[o][3].z + h3v.w * wreg[o][3].w;
            part[o] = s;
        }
        #pragma unroll
        for (int o = 0; o < 8; ++o) {
            part[o] += __shfl_xor(part[o], 1, 64);
            part[o] += __shfl_xor(part[o], 2, 64);
            part[o] += __shfl_xor(part[o], 4, 64);
            part[o] += __shfl_xor(part[o], 8, 64);
        }
        float v0 = part[0] + b2v[0], v1 = part[1] + b2v[1];
        float v2 = part[2] + b2v[2], v3 = part[3] + b2v[3];
        float v4 = part[4] + b2v[4], v5 = part[5] + b2v[5];
        float v6 = part[6] + b2v[6], v7 = part[7] + b2v[7];
        float mx = fmaxf(fmaxf(fmaxf(v0, v1), fmaxf(v2, v3)),
                         fmaxf(fmaxf(v4, v5), fmaxf(v6, v7)));
        v0 = expf(v0 - mx); v1 = expf(v1 - mx); v2 = expf(v2 - mx); v3 = expf(v3 - mx);
        v4 = expf(v4 - mx); v5 = expf(v5 - mx); v6 = expf(v6 - mx); v7 = expf(v7 - mx);
        float inv = 1.f / ((v0 + v1 + v2 + v3) + (v4 + v5 + v6 + v7));
        if (kl == 0 && grow < N_NODES) {
            float4 o0 = make_float4(v0 * inv, v1 * inv, v2 * inv, v3 * inv);
            float4 o1 = make_float4(v4 * inv, v5 * inv, v6 * inv, v7 * inv);
            ((float4*)(out + (size_t)grow * 8))[0] = o0;
            ((float4*)(out + (size_t)grow * 8))[1] = o1;
        }
    }
}

// ---------------------------------------------------------------- launcher
static inline size_t align_up(size_t x) { return (x + 255) & ~(size_t)255; }

extern "C" void kernel_launch(void* const* d_in, const int* in_sizes, int n_in,
                              void* d_out, int out_size, void* d_ws, size_t ws_size,
                              hipStream_t stream) {
    const float* x   = (const float*)d_in[0];
    const int*   ei  = (const int*)d_in[1];
    const float* W1l = (const float*)d_in[2];
    const float* b1  = (const float*)d_in[3];
    const float* W1r = (const float*)d_in[4];
    const float* W2l = (const float*)d_in[5];
    const float* b2  = (const float*)d_in[6];
    const float* W2r = (const float*)d_in[7];
    const float* Wm1 = (const float*)d_in[8];
    const float* bm1 = (const float*)d_in[9];
    const float* Wm2 = (const float*)d_in[10];
    const float* bm2 = (const float*)d_in[11];
    float* out = (float*)d_out;

    const size_t NF = (size_t)N_NODES * D;
    const size_t NW = (size_t)D * D;

    char* w = (char*)d_ws;
    u16* x_hi  = (u16*)w; w += align_up(NF * 2);
    u16* x_lo  = (u16*)w; w += align_up(NF * 2);
    u16* mn_hi = (u16*)w; w += align_up(NF * 2 * 2);
    u16* mn_lo = mn_hi + NF;
    u16* h1_hi = (u16*)w; w += align_up(NF * 2);
    u16* h1_lo = (u16*)w; w += align_up(NF * 2);
    u16* h2_hi = (u16*)w; w += align_up(NF * 2);
    u16* h2_lo = (u16*)w; w += align_up(NF * 2);
    u16* wbuf  = (u16*)w; w += align_up(NW * 2 * 10);
    u16* w1l_h = wbuf + 0 * NW; u16* w1l_l = wbuf + 1 * NW;
    u16* w1r_h = wbuf + 2 * NW; u16* w1r_l = wbuf + 3 * NW;
    u16* w2l_h = wbuf + 4 * NW; u16* w2l_l = wbuf + 5 * NW;
    u16* w2r_h = wbuf + 6 * NW; u16* w2r_l = wbuf + 7 * NW;
    u16* wm1_h = wbuf + 8 * NW; u16* wm1_l = wbuf + 9 * NW;
    int* cnt     = (int*)w; w += align_up((size_t)N_NODES * 4);
    int* rowptr  = (int*)w; w += align_up((size_t)(N_NODES + 1) * 4);
    int* cursor  = (int*)w; w += align_up((size_t)N_NODES * 4);
    int* partial = (int*)w; w += align_up((size_t)49 * 1024 * 4);
    int* bsum    = (int*)w; w += align_up((size_t)64 * 4);
    int* boff    = (int*)w; w += align_up((size_t)64 * 4);
    int* esrc    = (int*)w; w += align_up((size_t)N_EDGES * 4);

    // raise dynamic-LDS cap for the 144 KB triple-buffer (one-time)
    static bool attr_done = false;
    if (!attr_done) {
        hipFuncSetAttribute((const void*)gemm_mfma,
                            hipFuncAttributeMaxDynamicSharedMemorySize,
                            NBUF * BUF_U16 * 2);
        hipFuncSetAttribute((const void*)gemm_mlp2,
                            hipFuncAttributeMaxDynamicSharedMemorySize,
                            NBUF * BUF_U16 * 2);
        attr_done = true;
    }

    // CSR build (cnt zeroing via async memset -- saves one launch)
    hipMemsetAsync(cnt, 0, (size_t)N_NODES * 4, stream);
    count_deg<<<(N_EDGES + 255) / 256, 256, 0, stream>>>(ei, cnt);
    scan1<<<49, 1024, 0, stream>>>(cnt, partial, bsum);
    scan2<<<1, 64, 0, stream>>>(bsum, boff, 49);
    scan3<<<(N_NODES + 256) / 256, 256, 0, stream>>>(partial, boff, rowptr, cursor);
    fill_edges<<<(N_EDGES + 255) / 256, 256, 0, stream>>>(ei, cursor, esrc);

    // operand splits: x + 5 weight matrices in ONE launch
    {
        int total = (int)(NF + 5 * NW);
        split_all<<<(total + 255) / 256, 256, 0, stream>>>(
            x,   x_hi,  x_lo,
            W1l, w1l_h, w1l_l,
            W1r, w1r_h, w1r_l,
            W2l, w2l_h, w2l_l,
            W2r, w2r_h, w2r_l,
            Wm1, wm1_h, wm1_l);
    }

    const int GEMM_LDS = NBUF * BUF_U16 * 2;   // 147456 B
    dim3 ggrid(392);   // 196 m-tiles x 2 n-tiles, XCD pair-swizzled in-kernel
    const int AGRID = 2048;                    // persistent grid-stride

    // Layer 1: aggregate bf16(x) hi-plane
    aggregate_bf16<<<AGRID, 256, 0, stream>>>(x_hi, rowptr, esrc, mn_hi, mn_lo);
    gemm_mfma<<<ggrid, 512, GEMM_LDS, stream>>>(mn_hi, mn_lo, x_hi, x_lo,
                                                w1l_h, w1l_l, w1r_h, w1r_l,
                                                b1, 512, h1_hi, h1_lo);
    // Layer 2: aggregate bf16(h1) hi-plane
    aggregate_bf16<<<AGRID, 256, 0, stream>>>(h1_hi, rowptr, esrc, mn_hi, mn_lo);
    gemm_mfma<<<ggrid, 512, GEMM_LDS, stream>>>(mn_hi, mn_lo, h1_hi, h1_lo,
                                                w2l_h, w2l_l, w2r_h, w2r_l,
                                                b2, 512, h2_hi, h2_lo);
    // MLP (K=256) fused with decoder + softmax
    gemm_mlp2<<<(N_NODES + 127) / 128, 512, GEMM_LDS, stream>>>(
        h2_hi, h2_lo, wm1_h, wm1_l, bm1, Wm2, bm2, out);
}

// Round 9
// 480.185 us; speedup vs baseline: 1.0258x; 1.0258x over previous
//
#include <hip/hip_runtime.h>
#include <math.h>

#define N_NODES 50000
#define N_EDGES 800000
#define D 256

typedef unsigned short u16;
typedef __attribute__((ext_vector_type(8))) __bf16 bf16x8;
typedef __attribute__((ext_vector_type(4))) float f32x4;

// GEMM tile geometry: 256x128 tile, 512 threads (8 waves 4m x 2n), BK=32.
// Per-buffer LDS (u16 units): Ah[0,8192) Al[8192,16384) Bh[16384,20480) Bl[20480,24576)
#define BUF_U16 24576
#define NBUF 3

// ---------------------------------------------------------------- helpers
__device__ __forceinline__ void split_hi_lo(float v, u16& h, u16& l) {
    unsigned u = __float_as_uint(v);
    unsigned hh = (u + 0x7fff + ((u >> 16) & 1)) >> 16;   // RNE bf16
    float hf = __uint_as_float(hh << 16);
    float res = v - hf;
    unsigned ul = __float_as_uint(res);
    unsigned ll = (ul + 0x7fff + ((ul >> 16) & 1)) >> 16;
    h = (u16)hh; l = (u16)ll;
}

__device__ __forceinline__ float bflo(unsigned u) { return __uint_as_float(u << 16); }
__device__ __forceinline__ float bfhi(unsigned u) { return __uint_as_float(u & 0xffff0000u); }

__device__ __forceinline__ void gl_lds16(const void* g, void* l) {
    __builtin_amdgcn_global_load_lds(
        (const __attribute__((address_space(1))) void*)g,
        (__attribute__((address_space(3))) void*)l, 16, 0, 0);
}

// ---------------------------------------------------------------- utilities
__global__ void count_deg(const int* __restrict__ ei, int* __restrict__ cnt) {
    int e = blockIdx.x * blockDim.x + threadIdx.x;
    if (e < N_EDGES) atomicAdd(&cnt[ei[N_EDGES + e]], 1);
}

__global__ void scan1(const int* __restrict__ cnt, int* __restrict__ partial,
                      int* __restrict__ bsum) {
    __shared__ int s[1024];
    int t = threadIdx.x, b = blockIdx.x;
    int gid = b * 1024 + t;
    int v = (gid < N_NODES) ? cnt[gid] : 0;
    s[t] = v;
    __syncthreads();
    for (int off = 1; off < 1024; off <<= 1) {
        int u = (t >= off) ? s[t - off] : 0;
        __syncthreads();
        s[t] += u;
        __syncthreads();
    }
    partial[gid] = s[t];
    if (t == 1023) bsum[b] = s[1023];
}

__global__ void scan2(const int* __restrict__ bsum, int* __restrict__ boff, int nb) {
    int t = threadIdx.x;
    int orig = (t < nb) ? bsum[t] : 0;
    int v = orig;
    #pragma unroll
    for (int off = 1; off < 64; off <<= 1) {
        int u = __shfl_up(v, off, 64);
        if (t >= off) v += u;
    }
    boff[t] = v - orig;
}

__global__ void scan3(const int* __restrict__ partial, const int* __restrict__ boff,
                      int* __restrict__ rowptr, int* __restrict__ cursor) {
    int i = blockIdx.x * blockDim.x + threadIdx.x;
    if (i <= N_NODES) {
        int val = 0;
        if (i > 0) val = partial[i - 1] + boff[(i - 1) >> 10];
        rowptr[i] = val;
        if (i < N_NODES) cursor[i] = val;
    }
}

__global__ void fill_edges(const int* __restrict__ ei, int* __restrict__ cursor,
                           int* __restrict__ esrc) {
    int e = blockIdx.x * blockDim.x + threadIdx.x;
    if (e < N_EDGES) {
        int p = atomicAdd(&cursor[ei[N_EDGES + e]], 1);
        esrc[p] = ei[e];
    }
}

// ------------------------------------------- fused fp32 -> bf16 hi/lo split
// One launch covers x (NF elems) + 5 weight matrices (NW = 65536 = 1<<16
// elems each). Segment decode is shift/mask; per-element op identical to the
// old per-tensor split_bf16 (bitwise-identical outputs).
#define NF_CONST (N_NODES * D)                 // 12,800,000
__global__ void split_all(const float* __restrict__ x,  u16* __restrict__ xh,  u16* __restrict__ xl,
                          const float* __restrict__ w0, u16* __restrict__ w0h, u16* __restrict__ w0l,
                          const float* __restrict__ w1, u16* __restrict__ w1h, u16* __restrict__ w1l,
                          const float* __restrict__ w2, u16* __restrict__ w2h, u16* __restrict__ w2l,
                          const float* __restrict__ w3, u16* __restrict__ w3h, u16* __restrict__ w3l,
                          const float* __restrict__ w4, u16* __restrict__ w4h, u16* __restrict__ w4l) {
    int i = blockIdx.x * blockDim.x + threadIdx.x;
    const float* src; u16* dh; u16* dl; int k;
    if (i < NF_CONST) {
        src = x; dh = xh; dl = xl; k = i;
    } else {
        int r = i - NF_CONST;
        int j = r >> 16;                      // which weight matrix
        k = r & 65535;
        switch (j) {
            case 0: src = w0; dh = w0h; dl = w0l; break;
            case 1: src = w1; dh = w1h; dl = w1l; break;
            case 2: src = w2; dh = w2h; dl = w2l; break;
            case 3: src = w3; dh = w3h; dl = w3l; break;
            default: if (j > 4) return;
                    src = w4; dh = w4h; dl = w4l; break;
        }
    }
    u16 h, l; split_hi_lo(src[k], h, l);
    dh[k] = h; dl[k] = l;
}

// ---------------------------------------------------------------- aggregation
// One node per wave (R7 structure -- measured best: 58.6us, 3.95 TB/s).
// The 12.5K-block dispatch IS the latency-hiding mechanism: a finishing wave
// is replaced by a fresh block whose rowptr+gathers issue immediately.
// (R8's persistent grid-stride serialized rowptr->gather per wave: -13%.)
// Lanes 0-31 even edges, 32-63 odd; 16B/lane/edge; 8 gathers in flight.
__global__ __launch_bounds__(256) void aggregate_bf16(const u16* __restrict__ in_hi,
        const int* __restrict__ rowptr, const int* __restrict__ esrc,
        u16* __restrict__ ohi, u16* __restrict__ olo) {
    int node = blockIdx.x * 4 + (threadIdx.x >> 6);
    if (node >= N_NODES) return;
    int lane = threadIdx.x & 63;
    int half = lane >> 5;            // 0: even edges, 1: odd edges
    int sub = lane & 31;             // 16B chunk within the 512B row
    int beg = rowptr[node], end = rowptr[node + 1];
    const u16* rowp = in_hi + sub * 8;

    float a0 = 0.f, a1 = 0.f, a2 = 0.f, a3 = 0.f;
    float a4 = 0.f, a5 = 0.f, a6 = 0.f, a7 = 0.f;

#define ACC8(v) \
    a0 += bflo(v.x); a1 += bfhi(v.x); a2 += bflo(v.y); a3 += bfhi(v.y); \
    a4 += bflo(v.z); a5 += bfhi(v.z); a6 += bflo(v.w); a7 += bfhi(v.w);

    int j = beg;
    for (; j + 16 <= end; j += 16) {
        int i0 = esrc[j +  0 + half];
        int i1 = esrc[j +  2 + half];
        int i2 = esrc[j +  4 + half];
        int i3 = esrc[j +  6 + half];
        int i4 = esrc[j +  8 + half];
        int i5 = esrc[j + 10 + half];
        int i6 = esrc[j + 12 + half];
        int i7 = esrc[j + 14 + half];
        uint4 r0 = *(const uint4*)(rowp + (size_t)i0 * D);
        uint4 r1 = *(const uint4*)(rowp + (size_t)i1 * D);
        uint4 r2 = *(const uint4*)(rowp + (size_t)i2 * D);
        uint4 r3 = *(const uint4*)(rowp + (size_t)i3 * D);
        uint4 r4 = *(const uint4*)(rowp + (size_t)i4 * D);
        uint4 r5 = *(const uint4*)(rowp + (size_t)i5 * D);
        uint4 r6 = *(const uint4*)(rowp + (size_t)i6 * D);
        uint4 r7 = *(const uint4*)(rowp + (size_t)i7 * D);
        ACC8(r0); ACC8(r1); ACC8(r2); ACC8(r3);
        ACC8(r4); ACC8(r5); ACC8(r6); ACC8(r7);
    }
    for (; j + 8 <= end; j += 8) {
        int i0 = esrc[j + 0 + half];
        int i1 = esrc[j + 2 + half];
        int i2 = esrc[j + 4 + half];
        int i3 = esrc[j + 6 + half];
        uint4 r0 = *(const uint4*)(rowp + (size_t)i0 * D);
        uint4 r1 = *(const uint4*)(rowp + (size_t)i1 * D);
        uint4 r2 = *(const uint4*)(rowp + (size_t)i2 * D);
        uint4 r3 = *(const uint4*)(rowp + (size_t)i3 * D);
        ACC8(r0); ACC8(r1); ACC8(r2); ACC8(r3);
    }
    for (; j < end; j += 2) {
        int e = j + half;
        if (e < end) {
            uint4 r = *(const uint4*)(rowp + (size_t)esrc[e] * D);
            ACC8(r);
        }
    }
#undef ACC8

    // combine even-edge half (lanes 0-31) with odd-edge half (lanes 32-63)
    a0 += __shfl_xor(a0, 32, 64); a1 += __shfl_xor(a1, 32, 64);
    a2 += __shfl_xor(a2, 32, 64); a3 += __shfl_xor(a3, 32, 64);
    a4 += __shfl_xor(a4, 32, 64); a5 += __shfl_xor(a5, 32, 64);
    a6 += __shfl_xor(a6, 32, 64); a7 += __shfl_xor(a7, 32, 64);

    if (lane < 32) {
        float inv = 1.f / (float)max(end - beg, 1);
        float m[8] = { a0 * inv, a1 * inv, a2 * inv, a3 * inv,
                       a4 * inv, a5 * inv, a6 * inv, a7 * inv };
        u16 h[8], l[8];
        #pragma unroll
        for (int k = 0; k < 8; ++k) split_hi_lo(m[k], h[k], l[k]);
        size_t o = (size_t)node * D + lane * 8;
        *(uint4*)(ohi + o) = make_uint4(h[0] | (h[1] << 16), h[2] | (h[3] << 16),
                                        h[4] | (h[5] << 16), h[6] | (h[7] << 16));
        *(uint4*)(olo + o) = make_uint4(l[0] | (l[1] << 16), l[2] | (l[3] << 16),
                                        l[4] | (l[5] << 16), l[6] | (l[7] << 16));
    }
}

// ---------------------------------------------------------------- MFMA GEMM
// C[m,n] = act( A1[m,:]@B1[n,:] + A2[m,:]@B2[n,:] + bias[n] ), all operands
// split into bf16 hi/lo pairs; 3-term MFMA (hh + hl + lh) ~= fp32 precision.
// Depth-3 pipeline (T3+T4): 256x128 tile, 512 threads, 3 x 48 KB LDS buffers.
// Per step s: wait vmcnt(6) -> barrier -> stage s+2 -> 48 MFMA.
// Epilogue: C tile staged in LDS (buffers dead) then 16B/lane coalesced stores.
__device__ __forceinline__ void stage256(u16* buf,
        const u16* __restrict__ Ah, const u16* __restrict__ Al,
        const u16* __restrict__ Bh, const u16* __restrict__ Bl,
        int ks, int m0, int n0, int t) {
    int tr = t >> 2;                          // 0..127
    int g  = (t & 3) ^ ((t >> 3) & 3);        // pre-swizzled k-chunk
    size_t boff = (size_t)(n0 + tr) * D + ks + g * 8;
    gl_lds16(Bh + boff, buf + 16384 + t * 8);
    gl_lds16(Bl + boff, buf + 20480 + t * 8);
    #pragma unroll
    for (int r = 0; r < 2; ++r) {
        int arow = m0 + r * 128 + tr; if (arow >= N_NODES) arow = N_NODES - 1;
        size_t aoff = (size_t)arow * D + ks + g * 8;
        gl_lds16(Ah + aoff, buf + r * 4096 + t * 8);
        gl_lds16(Al + aoff, buf + 8192 + r * 4096 + t * 8);
    }
}

__global__ __launch_bounds__(512, 1) void gemm_mfma(
        const u16* __restrict__ A1h, const u16* __restrict__ A1l,
        const u16* __restrict__ A2h, const u16* __restrict__ A2l,
        const u16* __restrict__ B1h, const u16* __restrict__ B1l,
        const u16* __restrict__ B2h, const u16* __restrict__ B2l,
        const float* __restrict__ bias, int K,
        u16* __restrict__ Chi, u16* __restrict__ Clo) {
    extern __shared__ u16 sh[];               // 3 x 24576 u16 = 144 KB
    const int t = threadIdx.x;
    const int lane = t & 63;
    const int w = t >> 6;                     // 0..7
    const int wm = (w >> 1) * 64, wn = (w & 1) * 64;

    // XCD pair-swizzle: 392 blocks = 196 m-tiles x 2 n-tiles; (m,0)/(m,1)
    // are 8 dispatch slots apart -> same XCD, A-tile shared through its L2.
    int bid = blockIdx.x;
    int m_idx, n_idx;
    if (bid < 384) {
        m_idx = (bid >> 4) * 8 + (bid & 7);
        n_idx = (bid >> 3) & 1;
    } else {
        int r = bid - 384;                    // tail: 4 m-values x 2 n
        m_idx = 192 + (r & 3);
        n_idx = r >> 2;
    }
    const int m0 = m_idx * 256, n0 = n_idx * 128;

    f32x4 acc[4][4] = {};

    const int lm = lane & 15;
    const int sw = ((lane >> 4) ^ ((lm >> 1) & 3)) * 8;
    const int nsteps = K >> 5;

    // prologue: stage steps 0 and 1 (k0=0,32 always < 256 -> operand set 1)
    stage256(sh,           A1h, A1l, B1h, B1l,  0, m0, n0, t);
    stage256(sh + BUF_U16, A1h, A1l, B1h, B1l, 32, m0, n0, t);

    int cur = 0;
    for (int s = 0; s < nsteps; ++s) {
        if (s + 1 < nsteps) {
            asm volatile("s_waitcnt vmcnt(6)" ::: "memory");
        } else {
            asm volatile("s_waitcnt vmcnt(0)" ::: "memory");
        }
        __builtin_amdgcn_s_barrier();
        __builtin_amdgcn_sched_barrier(0);

        if (s + 2 < nsteps) {
            int sb = cur + 2; if (sb >= NBUF) sb -= NBUF;
            int ksg = (s + 2) * 32;
            if (ksg < 256) stage256(sh + sb * BUF_U16, A1h, A1l, B1h, B1l, ksg,       m0, n0, t);
            else           stage256(sh + sb * BUF_U16, A2h, A2l, B2h, B2l, ksg - 256, m0, n0, t);
        }

        const u16* buf = sh + cur * BUF_U16;
        bf16x8 ah[4], al[4], bh[4], bl[4];
        #pragma unroll
        for (int i = 0; i < 4; ++i) {
            int offA = (wm + i * 16 + lm) * 32 + sw;
            ah[i] = *(const bf16x8*)(buf + offA);
            al[i] = *(const bf16x8*)(buf + 8192 + offA);
            int offB = (wn + i * 16 + lm) * 32 + sw;
            bh[i] = *(const bf16x8*)(buf + 16384 + offB);
            bl[i] = *(const bf16x8*)(buf + 20480 + offB);
        }
        __builtin_amdgcn_s_setprio(1);
        #pragma unroll
        for (int i = 0; i < 4; ++i) {
            #pragma unroll
            for (int j = 0; j < 4; ++j) {
                acc[i][j] = __builtin_amdgcn_mfma_f32_16x16x32_bf16(ah[i], bh[j], acc[i][j], 0, 0, 0);
                acc[i][j] = __builtin_amdgcn_mfma_f32_16x16x32_bf16(ah[i], bl[j], acc[i][j], 0, 0, 0);
                acc[i][j] = __builtin_amdgcn_mfma_f32_16x16x32_bf16(al[i], bh[j], acc[i][j], 0, 0, 0);
            }
        }
        __builtin_amdgcn_s_setprio(0);

        cur = (cur == NBUF - 1) ? 0 : cur + 1;
    }

    // ---- epilogue: stage C tile in LDS (hi at [0,32768), lo at [32768,65536))
    __syncthreads();
    const int q = lane >> 4;
    #pragma unroll
    for (int j = 0; j < 4; ++j) {
        int col = wn + j * 16 + lm;
        float bb = bias[n0 + col];
        #pragma unroll
        for (int i = 0; i < 4; ++i) {
            #pragma unroll
            for (int r = 0; r < 4; ++r) {
                int row = wm + i * 16 + q * 4 + r;
                float v = fmaxf(acc[i][j][r] + bb, 0.f);
                u16 h, l; split_hi_lo(v, h, l);
                sh[row * 128 + col] = h;
                sh[32768 + row * 128 + col] = l;
            }
        }
    }
    __syncthreads();
    // coalesced 16B/lane stores: 4096 chunks per plane (256 rows x 16 chunks)
    for (int c = t; c < 4096; c += 512) {
        int row = c >> 4;
        int off = (c & 15) * 8;
        int grow = m0 + row;
        if (grow < N_NODES) {
            size_t o = (size_t)grow * D + n0 + off;
            *(uint4*)(Chi + o) = *(const uint4*)(sh + row * 128 + off);
            *(uint4*)(Clo + o) = *(const uint4*)(sh + 32768 + row * 128 + off);
        }
    }
}

// ----------------------------------------------------- fused GEMM3 + MLP2
// h3 = relu(h2 @ Wm1^T + bm1) as a 128x256 tile (full N in one block, K=256,
// depth-3/vmcnt(6) schedule); tile staged in LDS at padded stride 260.
// Decoder: distributed-k, 16 lanes per row; Wm2 slice preloaded to regs;
// 4-deep shfl_xor reduce + in-lane softmax; lane kl==0 stores 32 B.
__device__ __forceinline__ void stage_mlp(u16* buf,
        const u16* __restrict__ Ah, const u16* __restrict__ Al,
        const u16* __restrict__ Bh, const u16* __restrict__ Bl,
        int ks, int m0, int t) {
    int tr = t >> 2;                          // A: 128 rows, 1 load/plane
    int g  = (t & 3) ^ ((t >> 3) & 3);
    int arow = m0 + tr; if (arow >= N_NODES) arow = N_NODES - 1;
    size_t aoff = (size_t)arow * D + ks + g * 8;
    gl_lds16(Ah + aoff, buf + t * 8);                 // [0,4096)
    gl_lds16(Al + aoff, buf + 4096 + t * 8);          // [4096,8192)
    #pragma unroll
    for (int r = 0; r < 2; ++r) {             // B: 256 rows, 2 rounds/plane
        int u = r * 512 + t;                  // lane-linear dest per round
        int brow = u >> 2;
        int gb = (u & 3) ^ ((u >> 3) & 3);
        size_t boff = (size_t)brow * D + ks + gb * 8;
        gl_lds16(Bh + boff, buf + 8192  + u * 8);     // [8192,16384)
        gl_lds16(Bl + boff, buf + 16384 + u * 8);     // [16384,24576)
    }
}

__global__ __launch_bounds__(512, 1) void gemm_mlp2(
        const u16* __restrict__ Ah, const u16* __restrict__ Al,
        const u16* __restrict__ Bh, const u16* __restrict__ Bl,
        const float* __restrict__ bm1, const float* __restrict__ Wm2,
        const float* __restrict__ bm2, float* __restrict__ out) {
    extern __shared__ u16 sh[];               // 144 KB
    const int t = threadIdx.x;
    const int lane = t & 63;
    const int w = t >> 6;                     // 8 waves: 2m x 4n
    const int wm = (w >> 2) * 64, wn = (w & 3) * 64;
    const int m0 = blockIdx.x * 128;

    f32x4 acc[4][4] = {};
    const int lm = lane & 15;
    const int sw = ((lane >> 4) ^ ((lm >> 1) & 3)) * 8;
    const int nsteps = 8;                     // K = 256

    stage_mlp(sh,           Ah, Al, Bh, Bl,  0, m0, t);
    stage_mlp(sh + BUF_U16, Ah, Al, Bh, Bl, 32, m0, t);

    int cur = 0;
    for (int s = 0; s < nsteps; ++s) {
        if (s + 1 < nsteps) {
            asm volatile("s_waitcnt vmcnt(6)" ::: "memory");
        } else {
            asm volatile("s_waitcnt vmcnt(0)" ::: "memory");
        }
        __builtin_amdgcn_s_barrier();
        __builtin_amdgcn_sched_barrier(0);

        if (s + 2 < nsteps) {
            int sb = cur + 2; if (sb >= NBUF) sb -= NBUF;
            stage_mlp(sh + sb * BUF_U16, Ah, Al, Bh, Bl, (s + 2) * 32, m0, t);
        }

        const u16* buf = sh + cur * BUF_U16;
        bf16x8 a_h[4], a_l[4], b_h[4], b_l[4];
        #pragma unroll
        for (int i = 0; i < 4; ++i) {
            int offA = (wm + i * 16 + lm) * 32 + sw;
            a_h[i] = *(const bf16x8*)(buf + offA);
            a_l[i] = *(const bf16x8*)(buf + 4096 + offA);
            int offB = (wn + i * 16 + lm) * 32 + sw;
            b_h[i] = *(const bf16x8*)(buf + 8192 + offB);
            b_l[i] = *(const bf16x8*)(buf + 16384 + offB);
        }
        __builtin_amdgcn_s_setprio(1);
        #pragma unroll
        for (int i = 0; i < 4; ++i) {
            #pragma unroll
            for (int j = 0; j < 4; ++j) {
                acc[i][j] = __builtin_amdgcn_mfma_f32_16x16x32_bf16(a_h[i], b_h[j], acc[i][j], 0, 0, 0);
                acc[i][j] = __builtin_amdgcn_mfma_f32_16x16x32_bf16(a_h[i], b_l[j], acc[i][j], 0, 0, 0);
                acc[i][j] = __builtin_amdgcn_mfma_f32_16x16x32_bf16(a_l[i], b_h[j], acc[i][j], 0, 0, 0);
            }
        }
        __builtin_amdgcn_s_setprio(0);

        cur = (cur == NBUF - 1) ? 0 : cur + 1;
    }

    // ---- stage h3 tile (128 x 260-padded fp32 = 133 KB) in LDS
    __syncthreads();
    float* h3s = (float*)sh;
    const int q = lane >> 4;
    #pragma unroll
    for (int j = 0; j < 4; ++j) {
        int col = wn + j * 16 + lm;
        float bb = bm1[col];
        #pragma unroll
        for (int i = 0; i < 4; ++i) {
            #pragma unroll
            for (int r = 0; r < 4; ++r) {
                int row = wm + i * 16 + q * 4 + r;
                h3s[row * 260 + col] = fmaxf(acc[i][j][r] + bb, 0.f);
            }
        }
    }
    __syncthreads();

    // ---- distributed-k decoder + softmax
    const int kl = lane & 15;                 // fixed k-window (16 floats)
    const int sr = lane >> 4;                 // sub-row 0..3

    float4 wreg[8][4];
    float b2v[8];
    #pragma unroll
    for (int o = 0; o < 8; ++o) {
        b2v[o] = bm2[o];
        #pragma unroll
        for (int c = 0; c < 4; ++c)
            wreg[o][c] = *(const float4*)(Wm2 + o * D + kl * 16 + c * 4);
    }

    #pragma unroll
    for (int p = 0; p < 4; ++p) {
        int row  = w * 16 + p * 4 + sr;
        int grow = m0 + row;
        const float* hrow = h3s + row * 260 + kl * 16;
        float4 h0 = *(const float4*)(hrow);
        float4 h1 = *(const float4*)(hrow + 4);
        float4 h2 = *(const float4*)(hrow + 8);
        float4 h3v = *(const float4*)(hrow + 12);
        float part[8];
        #pragma unroll
        for (int o = 0; o < 8; ++o) {
            float s;
            s  = h0.x * wreg[o][0].x + h0.y * wreg[o][0].y
               + h0.z * wreg[o][0].z + h0.w * wreg[o][0].w;
            s += h1.x * wreg[o][1].x + h1.y * wreg[o][1].y
               + h1.z * wreg[o][1].z + h1.w * wreg[o][1].w;
            s += h2.x * wreg[o][2].x + h2.y * wreg[o][2].y
               + h2.z * wreg[o][2].z + h2.w * wreg[o][2].w;
            s += h3v.x * wreg[o][3].x + h3v.y * wreg[o][3].y
               + h3v.z * wreg[o][3].z + h3v.w * wreg[o][3].w;
            part[o] = s;
        }
        #pragma unroll
        for (int o = 0; o < 8; ++o) {
            part[o] += __shfl_xor(part[o], 1, 64);
            part[o] += __shfl_xor(part[o], 2, 64);
            part[o] += __shfl_xor(part[o], 4, 64);
            part[o] += __shfl_xor(part[o], 8, 64);
        }
        float v0 = part[0] + b2v[0], v1 = part[1] + b2v[1];
        float v2 = part[2] + b2v[2], v3 = part[3] + b2v[3];
        float v4 = part[4] + b2v[4], v5 = part[5] + b2v[5];
        float v6 = part[6] + b2v[6], v7 = part[7] + b2v[7];
        float mx = fmaxf(fmaxf(fmaxf(v0, v1), fmaxf(v2, v3)),
                         fmaxf(fmaxf(v4, v5), fmaxf(v6, v7)));
        v0 = expf(v0 - mx); v1 = expf(v1 - mx); v2 = expf(v2 - mx); v3 = expf(v3 - mx);
        v4 = expf(v4 - mx); v5 = expf(v5 - mx); v6 = expf(v6 - mx); v7 = expf(v7 - mx);
        float inv = 1.f / ((v0 + v1 + v2 + v3) + (v4 + v5 + v6 + v7));
        if (kl == 0 && grow < N_NODES) {
            float4 o0 = make_float4(v0 * inv, v1 * inv, v2 * inv, v3 * inv);
            float4 o1 = make_float4(v4 * inv, v5 * inv, v6 * inv, v7 * inv);
            ((float4*)(out + (size_t)grow * 8))[0] = o0;
            ((float4*)(out + (size_t)grow * 8))[1] = o1;
        }
    }
}

// ---------------------------------------------------------------- launcher
static inline size_t align_up(size_t x) { return (x + 255) & ~(size_t)255; }

extern "C" void kernel_launch(void* const* d_in, const int* in_sizes, int n_in,
                              void* d_out, int out_size, void* d_ws, size_t ws_size,
                              hipStream_t stream) {
    const float* x   = (const float*)d_in[0];
    const int*   ei  = (const int*)d_in[1];
    const float* W1l = (const float*)d_in[2];
    const float* b1  = (const float*)d_in[3];
    const float* W1r = (const float*)d_in[4];
    const float* W2l = (const float*)d_in[5];
    const float* b2  = (const float*)d_in[6];
    const float* W2r = (const float*)d_in[7];
    const float* Wm1 = (const float*)d_in[8];
    const float* bm1 = (const float*)d_in[9];
    const float* Wm2 = (const float*)d_in[10];
    const float* bm2 = (const float*)d_in[11];
    float* out = (float*)d_out;

    const size_t NF = (size_t)N_NODES * D;
    const size_t NW = (size_t)D * D;

    char* w = (char*)d_ws;
    u16* x_hi  = (u16*)w; w += align_up(NF * 2);
    u16* x_lo  = (u16*)w; w += align_up(NF * 2);
    u16* mn_hi = (u16*)w; w += align_up(NF * 2 * 2);
    u16* mn_lo = mn_hi + NF;
    u16* h1_hi = (u16*)w; w += align_up(NF * 2);
    u16* h1_lo = (u16*)w; w += align_up(NF * 2);
    u16* h2_hi = (u16*)w; w += align_up(NF * 2);
    u16* h2_lo = (u16*)w; w += align_up(NF * 2);
    u16* wbuf  = (u16*)w; w += align_up(NW * 2 * 10);
    u16* w1l_h = wbuf + 0 * NW; u16* w1l_l = wbuf + 1 * NW;
    u16* w1r_h = wbuf + 2 * NW; u16* w1r_l = wbuf + 3 * NW;
    u16* w2l_h = wbuf + 4 * NW; u16* w2l_l = wbuf + 5 * NW;
    u16* w2r_h = wbuf + 6 * NW; u16* w2r_l = wbuf + 7 * NW;
    u16* wm1_h = wbuf + 8 * NW; u16* wm1_l = wbuf + 9 * NW;
    int* cnt     = (int*)w; w += align_up((size_t)N_NODES * 4);
    int* rowptr  = (int*)w; w += align_up((size_t)(N_NODES + 1) * 4);
    int* cursor  = (int*)w; w += align_up((size_t)N_NODES * 4);
    int* partial = (int*)w; w += align_up((size_t)49 * 1024 * 4);
    int* bsum    = (int*)w; w += align_up((size_t)64 * 4);
    int* boff    = (int*)w; w += align_up((size_t)64 * 4);
    int* esrc    = (int*)w; w += align_up((size_t)N_EDGES * 4);

    // raise dynamic-LDS cap for the 144 KB triple-buffer (one-time)
    static bool attr_done = false;
    if (!attr_done) {
        hipFuncSetAttribute((const void*)gemm_mfma,
                            hipFuncAttributeMaxDynamicSharedMemorySize,
                            NBUF * BUF_U16 * 2);
        hipFuncSetAttribute((const void*)gemm_mlp2,
                            hipFuncAttributeMaxDynamicSharedMemorySize,
                            NBUF * BUF_U16 * 2);
        attr_done = true;
    }

    // CSR build (cnt zeroing via async memset)
    hipMemsetAsync(cnt, 0, (size_t)N_NODES * 4, stream);
    count_deg<<<(N_EDGES + 255) / 256, 256, 0, stream>>>(ei, cnt);
    scan1<<<49, 1024, 0, stream>>>(cnt, partial, bsum);
    scan2<<<1, 64, 0, stream>>>(bsum, boff, 49);
    scan3<<<(N_NODES + 256) / 256, 256, 0, stream>>>(partial, boff, rowptr, cursor);
    fill_edges<<<(N_EDGES + 255) / 256, 256, 0, stream>>>(ei, cursor, esrc);

    // operand splits: x + 5 weight matrices in ONE launch
    {
        int total = (int)(NF + 5 * NW);
        split_all<<<(total + 255) / 256, 256, 0, stream>>>(
            x,   x_hi,  x_lo,
            W1l, w1l_h, w1l_l,
            W1r, w1r_h, w1r_l,
            W2l, w2l_h, w2l_l,
            W2r, w2r_h, w2r_l,
            Wm1, wm1_h, wm1_l);
    }

    const int GEMM_LDS = NBUF * BUF_U16 * 2;   // 147456 B
    dim3 ggrid(392);   // 196 m-tiles x 2 n-tiles, XCD pair-swizzled in-kernel
    int agrid = (N_NODES + 3) / 4;             // one node per wave (12.5K blocks)

    // Layer 1: aggregate bf16(x) hi-plane
    aggregate_bf16<<<agrid, 256, 0, stream>>>(x_hi, rowptr, esrc, mn_hi, mn_lo);
    gemm_mfma<<<ggrid, 512, GEMM_LDS, stream>>>(mn_hi, mn_lo, x_hi, x_lo,
                                                w1l_h, w1l_l, w1r_h, w1r_l,
                                                b1, 512, h1_hi, h1_lo);
    // Layer 2: aggregate bf16(h1) hi-plane
    aggregate_bf16<<<agrid, 256, 0, stream>>>(h1_hi, rowptr, esrc, mn_hi, mn_lo);
    gemm_mfma<<<ggrid, 512, GEMM_LDS, stream>>>(mn_hi, mn_lo, h1_hi, h1_lo,
                                                w2l_h, w2l_l, w2r_h, w2r_l,
                                                b2, 512, h2_hi, h2_lo);
    // MLP (K=256) fused with decoder + softmax
    gemm_mlp2<<<(N_NODES + 127) / 128, 512, GEMM_LDS, stream>>>(
        h2_hi, h2_lo, wm1_h, wm1_l, bm1, Wm2, bm2, out);
}

// Round 10
// 470.987 us; speedup vs baseline: 1.0459x; 1.0195x over previous
//
#include <hip/hip_runtime.h>
#include <math.h>

#define N_NODES 50000
#define N_EDGES 800000
#define D 256

typedef unsigned short u16;
typedef __attribute__((ext_vector_type(8))) __bf16 bf16x8;
typedef __attribute__((ext_vector_type(4))) float f32x4;

// ---- gemm_mfma geometry (R10): 256x256 tile, 512 threads (8 waves 2m x 4n),
// BK=32, grid 196 (tail-free: <=256 CUs, single block-round).
// LDS (u16 units): abuf[3] @ {0,16384,32768} (32KB each: Ah[0,8192) Al[8192,16384))
//                  bbuf[2] @ {49152,65536}   (32KB each: Bh/Bl same split)
// Total 160 KB. Epilogue reuses [0, 67584) as 256x264-padded u16 C-plane.
#define ABUF0 0
#define BBUF0 49152
#define GEMM_LDS_BYTES 163840

// ---- gemm_mlp2 geometry (unchanged): 128x256 tile, 3 x 24576-u16 buffers.
#define BUF_U16 24576
#define NBUF 3

// ---------------------------------------------------------------- helpers
__device__ __forceinline__ void split_hi_lo(float v, u16& h, u16& l) {
    unsigned u = __float_as_uint(v);
    unsigned hh = (u + 0x7fff + ((u >> 16) & 1)) >> 16;   // RNE bf16
    float hf = __uint_as_float(hh << 16);
    float res = v - hf;
    unsigned ul = __float_as_uint(res);
    unsigned ll = (ul + 0x7fff + ((ul >> 16) & 1)) >> 16;
    h = (u16)hh; l = (u16)ll;
}

__device__ __forceinline__ float bflo(unsigned u) { return __uint_as_float(u << 16); }
__device__ __forceinline__ float bfhi(unsigned u) { return __uint_as_float(u & 0xffff0000u); }

__device__ __forceinline__ void gl_lds16(const void* g, void* l) {
    __builtin_amdgcn_global_load_lds(
        (const __attribute__((address_space(1))) void*)g,
        (__attribute__((address_space(3))) void*)l, 16, 0, 0);
}

// ---------------------------------------------------------------- utilities
__global__ void count_deg(const int* __restrict__ ei, int* __restrict__ cnt) {
    int e = blockIdx.x * blockDim.x + threadIdx.x;
    if (e < N_EDGES) atomicAdd(&cnt[ei[N_EDGES + e]], 1);
}

__global__ void scan1(const int* __restrict__ cnt, int* __restrict__ partial,
                      int* __restrict__ bsum) {
    __shared__ int s[1024];
    int t = threadIdx.x, b = blockIdx.x;
    int gid = b * 1024 + t;
    int v = (gid < N_NODES) ? cnt[gid] : 0;
    s[t] = v;
    __syncthreads();
    for (int off = 1; off < 1024; off <<= 1) {
        int u = (t >= off) ? s[t - off] : 0;
        __syncthreads();
        s[t] += u;
        __syncthreads();
    }
    partial[gid] = s[t];
    if (t == 1023) bsum[b] = s[1023];
}

__global__ void scan2(const int* __restrict__ bsum, int* __restrict__ boff, int nb) {
    int t = threadIdx.x;
    int orig = (t < nb) ? bsum[t] : 0;
    int v = orig;
    #pragma unroll
    for (int off = 1; off < 64; off <<= 1) {
        int u = __shfl_up(v, off, 64);
        if (t >= off) v += u;
    }
    boff[t] = v - orig;
}

__global__ void scan3(const int* __restrict__ partial, const int* __restrict__ boff,
                      int* __restrict__ rowptr, int* __restrict__ cursor) {
    int i = blockIdx.x * blockDim.x + threadIdx.x;
    if (i <= N_NODES) {
        int val = 0;
        if (i > 0) val = partial[i - 1] + boff[(i - 1) >> 10];
        rowptr[i] = val;
        if (i < N_NODES) cursor[i] = val;
    }
}

__global__ void fill_edges(const int* __restrict__ ei, int* __restrict__ cursor,
                           int* __restrict__ esrc) {
    int e = blockIdx.x * blockDim.x + threadIdx.x;
    if (e < N_EDGES) {
        int p = atomicAdd(&cursor[ei[N_EDGES + e]], 1);
        esrc[p] = ei[e];
    }
}

// ------------------------------------------- fused fp32 -> bf16 hi/lo split
#define NF_CONST (N_NODES * D)                 // 12,800,000
__global__ void split_all(const float* __restrict__ x,  u16* __restrict__ xh,  u16* __restrict__ xl,
                          const float* __restrict__ w0, u16* __restrict__ w0h, u16* __restrict__ w0l,
                          const float* __restrict__ w1, u16* __restrict__ w1h, u16* __restrict__ w1l,
                          const float* __restrict__ w2, u16* __restrict__ w2h, u16* __restrict__ w2l,
                          const float* __restrict__ w3, u16* __restrict__ w3h, u16* __restrict__ w3l,
                          const float* __restrict__ w4, u16* __restrict__ w4h, u16* __restrict__ w4l) {
    int i = blockIdx.x * blockDim.x + threadIdx.x;
    const float* src; u16* dh; u16* dl; int k;
    if (i < NF_CONST) {
        src = x; dh = xh; dl = xl; k = i;
    } else {
        int r = i - NF_CONST;
        int j = r >> 16;                      // which weight matrix
        k = r & 65535;
        switch (j) {
            case 0: src = w0; dh = w0h; dl = w0l; break;
            case 1: src = w1; dh = w1h; dl = w1l; break;
            case 2: src = w2; dh = w2h; dl = w2l; break;
            case 3: src = w3; dh = w3h; dl = w3l; break;
            default: if (j > 4) return;
                    src = w4; dh = w4h; dl = w4l; break;
        }
    }
    u16 h, l; split_hi_lo(src[k], h, l);
    dh[k] = h; dl[k] = l;
}

// ---------------------------------------------------------------- aggregation
// One node per wave (measured best: 58.6us, 3.95 TB/s). The 12.5K-block
// dispatch IS the latency-hiding mechanism (R8's grid-stride: -13%).
__global__ __launch_bounds__(256) void aggregate_bf16(const u16* __restrict__ in_hi,
        const int* __restrict__ rowptr, const int* __restrict__ esrc,
        u16* __restrict__ ohi, u16* __restrict__ olo) {
    int node = blockIdx.x * 4 + (threadIdx.x >> 6);
    if (node >= N_NODES) return;
    int lane = threadIdx.x & 63;
    int half = lane >> 5;            // 0: even edges, 1: odd edges
    int sub = lane & 31;             // 16B chunk within the 512B row
    int beg = rowptr[node], end = rowptr[node + 1];
    const u16* rowp = in_hi + sub * 8;

    float a0 = 0.f, a1 = 0.f, a2 = 0.f, a3 = 0.f;
    float a4 = 0.f, a5 = 0.f, a6 = 0.f, a7 = 0.f;

#define ACC8(v) \
    a0 += bflo(v.x); a1 += bfhi(v.x); a2 += bflo(v.y); a3 += bfhi(v.y); \
    a4 += bflo(v.z); a5 += bfhi(v.z); a6 += bflo(v.w); a7 += bfhi(v.w);

    int j = beg;
    for (; j + 16 <= end; j += 16) {
        int i0 = esrc[j +  0 + half];
        int i1 = esrc[j +  2 + half];
        int i2 = esrc[j +  4 + half];
        int i3 = esrc[j +  6 + half];
        int i4 = esrc[j +  8 + half];
        int i5 = esrc[j + 10 + half];
        int i6 = esrc[j + 12 + half];
        int i7 = esrc[j + 14 + half];
        uint4 r0 = *(const uint4*)(rowp + (size_t)i0 * D);
        uint4 r1 = *(const uint4*)(rowp + (size_t)i1 * D);
        uint4 r2 = *(const uint4*)(rowp + (size_t)i2 * D);
        uint4 r3 = *(const uint4*)(rowp + (size_t)i3 * D);
        uint4 r4 = *(const uint4*)(rowp + (size_t)i4 * D);
        uint4 r5 = *(const uint4*)(rowp + (size_t)i5 * D);
        uint4 r6 = *(const uint4*)(rowp + (size_t)i6 * D);
        uint4 r7 = *(const uint4*)(rowp + (size_t)i7 * D);
        ACC8(r0); ACC8(r1); ACC8(r2); ACC8(r3);
        ACC8(r4); ACC8(r5); ACC8(r6); ACC8(r7);
    }
    for (; j + 8 <= end; j += 8) {
        int i0 = esrc[j + 0 + half];
        int i1 = esrc[j + 2 + half];
        int i2 = esrc[j + 4 + half];
        int i3 = esrc[j + 6 + half];
        uint4 r0 = *(const uint4*)(rowp + (size_t)i0 * D);
        uint4 r1 = *(const uint4*)(rowp + (size_t)i1 * D);
        uint4 r2 = *(const uint4*)(rowp + (size_t)i2 * D);
        uint4 r3 = *(const uint4*)(rowp + (size_t)i3 * D);
        ACC8(r0); ACC8(r1); ACC8(r2); ACC8(r3);
    }
    for (; j < end; j += 2) {
        int e = j + half;
        if (e < end) {
            uint4 r = *(const uint4*)(rowp + (size_t)esrc[e] * D);
            ACC8(r);
        }
    }
#undef ACC8

    a0 += __shfl_xor(a0, 32, 64); a1 += __shfl_xor(a1, 32, 64);
    a2 += __shfl_xor(a2, 32, 64); a3 += __shfl_xor(a3, 32, 64);
    a4 += __shfl_xor(a4, 32, 64); a5 += __shfl_xor(a5, 32, 64);
    a6 += __shfl_xor(a6, 32, 64); a7 += __shfl_xor(a7, 32, 64);

    if (lane < 32) {
        float inv = 1.f / (float)max(end - beg, 1);
        float m[8] = { a0 * inv, a1 * inv, a2 * inv, a3 * inv,
                       a4 * inv, a5 * inv, a6 * inv, a7 * inv };
        u16 h[8], l[8];
        #pragma unroll
        for (int k = 0; k < 8; ++k) split_hi_lo(m[k], h[k], l[k]);
        size_t o = (size_t)node * D + lane * 8;
        *(uint4*)(ohi + o) = make_uint4(h[0] | (h[1] << 16), h[2] | (h[3] << 16),
                                        h[4] | (h[5] << 16), h[6] | (h[7] << 16));
        *(uint4*)(olo + o) = make_uint4(l[0] | (l[1] << 16), l[2] | (l[3] << 16),
                                        l[4] | (l[5] << 16), l[6] | (l[7] << 16));
    }
}

// ---------------------------------------------------------------- MFMA GEMM
// R10: 256x256 tile, grid 196 (<=256 CUs -> NO block-wave tail; R9 ran 392
// blocks as 2 rounds, 2nd 53% full = ~24% idle). Mixed-depth pipeline keeps
// R9's 96 KB/block in flight: A 3-buffered (2-phase slack), B 2-buffered
// (1-phase slack, ~960cyc compute window). Queue-ordered waits: per step,
// vmcnt(4) retires {A(s),B(s)} leaving A(s+1); then stage B(s+1), A(s+2).
// B (full weight set) is block-invariant -> per-XCD L2-hot (~4MB fetch);
// A is read exactly once (pair-swizzle no longer needed).
__device__ __forceinline__ void stageA256(u16* abuf,
        const u16* __restrict__ Ah, const u16* __restrict__ Al,
        int ks, int m0, int t) {
    #pragma unroll
    for (int r = 0; r < 2; ++r) {
        int u = r * 512 + t;                  // 0..1023, lane-linear dest/call
        int row = u >> 2;                     // 0..255
        int g = (u & 3) ^ ((u >> 3) & 3);
        int arow = m0 + row; if (arow >= N_NODES) arow = N_NODES - 1;
        size_t off = (size_t)arow * D + ks + g * 8;
        gl_lds16(Ah + off, abuf + u * 8);             // [0,8192)
        gl_lds16(Al + off, abuf + 8192 + u * 8);      // [8192,16384)
    }
}

__device__ __forceinline__ void stageB256(u16* bbuf,
        const u16* __restrict__ Bh, const u16* __restrict__ Bl,
        int ks, int t) {
    #pragma unroll
    for (int r = 0; r < 2; ++r) {
        int u = r * 512 + t;
        int row = u >> 2;                     // 0..255 (all N rows)
        int g = (u & 3) ^ ((u >> 3) & 3);
        size_t off = (size_t)row * D + ks + g * 8;
        gl_lds16(Bh + off, bbuf + u * 8);
        gl_lds16(Bl + off, bbuf + 8192 + u * 8);
    }
}

__global__ __launch_bounds__(512, 1) void gemm_mfma(
        const u16* __restrict__ A1h, const u16* __restrict__ A1l,
        const u16* __restrict__ A2h, const u16* __restrict__ A2l,
        const u16* __restrict__ B1h, const u16* __restrict__ B1l,
        const u16* __restrict__ B2h, const u16* __restrict__ B2l,
        const float* __restrict__ bias, int K,
        u16* __restrict__ Chi, u16* __restrict__ Clo) {
    extern __shared__ u16 sh[];               // 160 KB
    const int t = threadIdx.x;
    const int lane = t & 63;
    const int w = t >> 6;                     // 8 waves: 2m x 4n
    const int wm = (w >> 2) * 128, wn = (w & 3) * 64;
    const int m0 = blockIdx.x * 256;

    f32x4 acc[8][4] = {};                     // 128 VGPRs

    const int lm = lane & 15;
    const int sw = ((lane >> 4) ^ ((lm >> 1) & 3)) * 8;
    const int nsteps = K >> 5;                // 16

    // prologue: A(0), B(0), A(1)  (k=0,32 always < 256 -> operand set 1)
    stageA256(sh + ABUF0,         A1h, A1l,  0, m0, t);
    stageB256(sh + BBUF0,         B1h, B1l,  0, t);
    stageA256(sh + ABUF0 + 16384, A1h, A1l, 32, m0, t);

    for (int s = 0; s < nsteps; ++s) {
        if (s + 1 < nsteps) {
            asm volatile("s_waitcnt vmcnt(4)" ::: "memory");   // A(s),B(s) done
        } else {
            asm volatile("s_waitcnt vmcnt(0)" ::: "memory");
        }
        __builtin_amdgcn_s_barrier();
        __builtin_amdgcn_sched_barrier(0);

        if (s + 1 < nsteps) {                 // B(s+1) first (queue order!)
            int kk = (s + 1) * 32;
            u16* bb = sh + BBUF0 + ((s + 1) & 1) * 16384;
            if (kk < 256) stageB256(bb, B1h, B1l, kk, t);
            else          stageB256(bb, B2h, B2l, kk - 256, t);
        }
        if (s + 2 < nsteps) {                 // then A(s+2)
            int kk = (s + 2) * 32;
            u16* ab = sh + ABUF0 + ((s + 2) % 3) * 16384;
            if (kk < 256) stageA256(ab, A1h, A1l, kk, m0, t);
            else          stageA256(ab, A2h, A2l, kk - 256, m0, t);
        }

        const u16* ab = sh + ABUF0 + (s % 3) * 16384;
        const u16* bb = sh + BBUF0 + (s & 1) * 16384;

        bf16x8 bhf[4], blf[4];
        #pragma unroll
        for (int j = 0; j < 4; ++j) {
            int offB = (wn + j * 16 + lm) * 32 + sw;
            bhf[j] = *(const bf16x8*)(bb + offB);
            blf[j] = *(const bf16x8*)(bb + 8192 + offB);
        }
        __builtin_amdgcn_s_setprio(1);
        #pragma unroll
        for (int ihalf = 0; ihalf < 2; ++ihalf) {     // i-split: cap VGPRs
            bf16x8 ahf[4], alf[4];
            #pragma unroll
            for (int ii = 0; ii < 4; ++ii) {
                int i = ihalf * 4 + ii;
                int offA = (wm + i * 16 + lm) * 32 + sw;
                ahf[ii] = *(const bf16x8*)(ab + offA);
                alf[ii] = *(const bf16x8*)(ab + 8192 + offA);
            }
            #pragma unroll
            for (int ii = 0; ii < 4; ++ii) {
                int i = ihalf * 4 + ii;
                #pragma unroll
                for (int j = 0; j < 4; ++j) {
                    acc[i][j] = __builtin_amdgcn_mfma_f32_16x16x32_bf16(ahf[ii], bhf[j], acc[i][j], 0, 0, 0);
                    acc[i][j] = __builtin_amdgcn_mfma_f32_16x16x32_bf16(ahf[ii], blf[j], acc[i][j], 0, 0, 0);
                    acc[i][j] = __builtin_amdgcn_mfma_f32_16x16x32_bf16(alf[ii], bhf[j], acc[i][j], 0, 0, 0);
                }
            }
        }
        __builtin_amdgcn_s_setprio(0);
    }

    // ---- epilogue: two passes (hi, lo); C plane staged at pad-264 stride
    // (528 B/row: 16B-aligned; rows 4 apart = 16 banks -> 2-way = free).
    const int q = lane >> 4;
    #pragma unroll
    for (int pl = 0; pl < 2; ++pl) {
        __syncthreads();
        #pragma unroll
        for (int j = 0; j < 4; ++j) {
            int col = wn + j * 16 + lm;
            float bb_ = bias[col];
            #pragma unroll
            for (int i = 0; i < 8; ++i) {
                #pragma unroll
                for (int r = 0; r < 4; ++r) {
                    int row = wm + i * 16 + q * 4 + r;
                    float v = fmaxf(acc[i][j][r] + bb_, 0.f);
                    u16 h, l; split_hi_lo(v, h, l);
                    sh[row * 264 + col] = pl ? l : h;
                }
            }
        }
        __syncthreads();
        u16* dst = pl ? Clo : Chi;
        for (int c = t; c < 8192; c += 512) {     // 256 rows x 32 16B-chunks
            int row = c >> 5;
            int off = (c & 31) * 8;
            int grow = m0 + row;
            if (grow < N_NODES)
                *(uint4*)(dst + (size_t)grow * D + off) =
                    *(const uint4*)(sh + row * 264 + off);
        }
    }
}

// ----------------------------------------------------- fused GEMM3 + MLP2
// (unchanged from R9: 128x256 tile, depth-3, pad-260 h3 stage, distributed-k
// decoder with reg-preloaded Wm2.)
__device__ __forceinline__ void stage_mlp(u16* buf,
        const u16* __restrict__ Ah, const u16* __restrict__ Al,
        const u16* __restrict__ Bh, const u16* __restrict__ Bl,
        int ks, int m0, int t) {
    int tr = t >> 2;                          // A: 128 rows, 1 load/plane
    int g  = (t & 3) ^ ((t >> 3) & 3);
    int arow = m0 + tr; if (arow >= N_NODES) arow = N_NODES - 1;
    size_t aoff = (size_t)arow * D + ks + g * 8;
    gl_lds16(Ah + aoff, buf + t * 8);                 // [0,4096)
    gl_lds16(Al + aoff, buf + 4096 + t * 8);          // [4096,8192)
    #pragma unroll
    for (int r = 0; r < 2; ++r) {             // B: 256 rows, 2 rounds/plane
        int u = r * 512 + t;                  // lane-linear dest per round
        int brow = u >> 2;
        int gb = (u & 3) ^ ((u >> 3) & 3);
        size_t boff = (size_t)brow * D + ks + gb * 8;
        gl_lds16(Bh + boff, buf + 8192  + u * 8);     // [8192,16384)
        gl_lds16(Bl + boff, buf + 16384 + u * 8);     // [16384,24576)
    }
}

__global__ __launch_bounds__(512, 1) void gemm_mlp2(
        const u16* __restrict__ Ah, const u16* __restrict__ Al,
        const u16* __restrict__ Bh, const u16* __restrict__ Bl,
        const float* __restrict__ bm1, const float* __restrict__ Wm2,
        const float* __restrict__ bm2, float* __restrict__ out) {
    extern __shared__ u16 sh[];               // 144 KB
    const int t = threadIdx.x;
    const int lane = t & 63;
    const int w = t >> 6;                     // 8 waves: 2m x 4n
    const int wm = (w >> 2) * 64, wn = (w & 3) * 64;
    const int m0 = blockIdx.x * 128;

    f32x4 acc[4][4] = {};
    const int lm = lane & 15;
    const int sw = ((lane >> 4) ^ ((lm >> 1) & 3)) * 8;
    const int nsteps = 8;                     // K = 256

    stage_mlp(sh,           Ah, Al, Bh, Bl,  0, m0, t);
    stage_mlp(sh + BUF_U16, Ah, Al, Bh, Bl, 32, m0, t);

    int cur = 0;
    for (int s = 0; s < nsteps; ++s) {
        if (s + 1 < nsteps) {
            asm volatile("s_waitcnt vmcnt(6)" ::: "memory");
        } else {
            asm volatile("s_waitcnt vmcnt(0)" ::: "memory");
        }
        __builtin_amdgcn_s_barrier();
        __builtin_amdgcn_sched_barrier(0);

        if (s + 2 < nsteps) {
            int sb = cur + 2; if (sb >= NBUF) sb -= NBUF;
            stage_mlp(sh + sb * BUF_U16, Ah, Al, Bh, Bl, (s + 2) * 32, m0, t);
        }

        const u16* buf = sh + cur * BUF_U16;
        bf16x8 a_h[4], a_l[4], b_h[4], b_l[4];
        #pragma unroll
        for (int i = 0; i < 4; ++i) {
            int offA = (wm + i * 16 + lm) * 32 + sw;
            a_h[i] = *(const bf16x8*)(buf + offA);
            a_l[i] = *(const bf16x8*)(buf + 4096 + offA);
            int offB = (wn + i * 16 + lm) * 32 + sw;
            b_h[i] = *(const bf16x8*)(buf + 8192 + offB);
            b_l[i] = *(const bf16x8*)(buf + 16384 + offB);
        }
        __builtin_amdgcn_s_setprio(1);
        #pragma unroll
        for (int i = 0; i < 4; ++i) {
            #pragma unroll
            for (int j = 0; j < 4; ++j) {
                acc[i][j] = __builtin_amdgcn_mfma_f32_16x16x32_bf16(a_h[i], b_h[j], acc[i][j], 0, 0, 0);
                acc[i][j] = __builtin_amdgcn_mfma_f32_16x16x32_bf16(a_h[i], b_l[j], acc[i][j], 0, 0, 0);
                acc[i][j] = __builtin_amdgcn_mfma_f32_16x16x32_bf16(a_l[i], b_h[j], acc[i][j], 0, 0, 0);
            }
        }
        __builtin_amdgcn_s_setprio(0);

        cur = (cur == NBUF - 1) ? 0 : cur + 1;
    }

    // ---- stage h3 tile (128 x 260-padded fp32 = 133 KB) in LDS
    __syncthreads();
    float* h3s = (float*)sh;
    const int q = lane >> 4;
    #pragma unroll
    for (int j = 0; j < 4; ++j) {
        int col = wn + j * 16 + lm;
        float bb = bm1[col];
        #pragma unroll
        for (int i = 0; i < 4; ++i) {
            #pragma unroll
            for (int r = 0; r < 4; ++r) {
                int row = wm + i * 16 + q * 4 + r;
                h3s[row * 260 + col] = fmaxf(acc[i][j][r] + bb, 0.f);
            }
        }
    }
    __syncthreads();

    // ---- distributed-k decoder + softmax
    const int kl = lane & 15;                 // fixed k-window (16 floats)
    const int sr = lane >> 4;                 // sub-row 0..3

    float4 wreg[8][4];
    float b2v[8];
    #pragma unroll
    for (int o = 0; o < 8; ++o) {
        b2v[o] = bm2[o];
        #pragma unroll
        for (int c = 0; c < 4; ++c)
            wreg[o][c] = *(const float4*)(Wm2 + o * D + kl * 16 + c * 4);
    }

    #pragma unroll
    for (int p = 0; p < 4; ++p) {
        int row  = w * 16 + p * 4 + sr;
        int grow = m0 + row;
        const float* hrow = h3s + row * 260 + kl * 16;
        float4 h0 = *(const float4*)(hrow);
        float4 h1 = *(const float4*)(hrow + 4);
        float4 h2 = *(const float4*)(hrow + 8);
        float4 h3v = *(const float4*)(hrow + 12);
        float part[8];
        #pragma unroll
        for (int o = 0; o < 8; ++o) {
            float s;
            s  = h0.x * wreg[o][0].x + h0.y * wreg[o][0].y
               + h0.z * wreg[o][0].z + h0.w * wreg[o][0].w;
            s += h1.x * wreg[o][1].x + h1.y * wreg[o][1].y
               + h1.z * wreg[o][1].z + h1.w * wreg[o][1].w;
            s += h2.x * wreg[o][2].x + h2.y * wreg[o][2].y
               + h2.z * wreg[o][2].z + h2.w * wreg[o][2].w;
            s += h3v.x * wreg[o][3].x + h3v.y * wreg[o][3].y
               + h3v.z * wreg[o][3].z + h3v.w * wreg[o][3].w;
            part[o] = s;
        }
        #pragma unroll
        for (int o = 0; o < 8; ++o) {
            part[o] += __shfl_xor(part[o], 1, 64);
            part[o] += __shfl_xor(part[o], 2, 64);
            part[o] += __shfl_xor(part[o], 4, 64);
            part[o] += __shfl_xor(part[o], 8, 64);
        }
        float v0 = part[0] + b2v[0], v1 = part[1] + b2v[1];
        float v2 = part[2] + b2v[2], v3 = part[3] + b2v[3];
        float v4 = part[4] + b2v[4], v5 = part[5] + b2v[5];
        float v6 = part[6] + b2v[6], v7 = part[7] + b2v[7];
        float mx = fmaxf(fmaxf(fmaxf(v0, v1), fmaxf(v2, v3)),
                         fmaxf(fmaxf(v4, v5), fmaxf(v6, v7)));
        v0 = expf(v0 - mx); v1 = expf(v1 - mx); v2 = expf(v2 - mx); v3 = expf(v3 - mx);
        v4 = expf(v4 - mx); v5 = expf(v5 - mx); v6 = expf(v6 - mx); v7 = expf(v7 - mx);
        float inv = 1.f / ((v0 + v1 + v2 + v3) + (v4 + v5 + v6 + v7));
        if (kl == 0 && grow < N_NODES) {
            float4 o0 = make_float4(v0 * inv, v1 * inv, v2 * inv, v3 * inv);
            float4 o1 = make_float4(v4 * inv, v5 * inv, v6 * inv, v7 * inv);
            ((float4*)(out + (size_t)grow * 8))[0] = o0;
            ((float4*)(out + (size_t)grow * 8))[1] = o1;
        }
    }
}

// ---------------------------------------------------------------- launcher
static inline size_t align_up(size_t x) { return (x + 255) & ~(size_t)255; }

extern "C" void kernel_launch(void* const* d_in, const int* in_sizes, int n_in,
                              void* d_out, int out_size, void* d_ws, size_t ws_size,
                              hipStream_t stream) {
    const float* x   = (const float*)d_in[0];
    const int*   ei  = (const int*)d_in[1];
    const float* W1l = (const float*)d_in[2];
    const float* b1  = (const float*)d_in[3];
    const float* W1r = (const float*)d_in[4];
    const float* W2l = (const float*)d_in[5];
    const float* b2  = (const float*)d_in[6];
    const float* W2r = (const float*)d_in[7];
    const float* Wm1 = (const float*)d_in[8];
    const float* bm1 = (const float*)d_in[9];
    const float* Wm2 = (const float*)d_in[10];
    const float* bm2 = (const float*)d_in[11];
    float* out = (float*)d_out;

    const size_t NF = (size_t)N_NODES * D;
    const size_t NW = (size_t)D * D;

    char* w = (char*)d_ws;
    u16* x_hi  = (u16*)w; w += align_up(NF * 2);
    u16* x_lo  = (u16*)w; w += align_up(NF * 2);
    u16* mn_hi = (u16*)w; w += align_up(NF * 2 * 2);
    u16* mn_lo = mn_hi + NF;
    u16* h1_hi = (u16*)w; w += align_up(NF * 2);
    u16* h1_lo = (u16*)w; w += align_up(NF * 2);
    u16* h2_hi = (u16*)w; w += align_up(NF * 2);
    u16* h2_lo = (u16*)w; w += align_up(NF * 2);
    u16* wbuf  = (u16*)w; w += align_up(NW * 2 * 10);
    u16* w1l_h = wbuf + 0 * NW; u16* w1l_l = wbuf + 1 * NW;
    u16* w1r_h = wbuf + 2 * NW; u16* w1r_l = wbuf + 3 * NW;
    u16* w2l_h = wbuf + 4 * NW; u16* w2l_l = wbuf + 5 * NW;
    u16* w2r_h = wbuf + 6 * NW; u16* w2r_l = wbuf + 7 * NW;
    u16* wm1_h = wbuf + 8 * NW; u16* wm1_l = wbuf + 9 * NW;
    int* cnt     = (int*)w; w += align_up((size_t)N_NODES * 4);
    int* rowptr  = (int*)w; w += align_up((size_t)(N_NODES + 1) * 4);
    int* cursor  = (int*)w; w += align_up((size_t)N_NODES * 4);
    int* partial = (int*)w; w += align_up((size_t)49 * 1024 * 4);
    int* bsum    = (int*)w; w += align_up((size_t)64 * 4);
    int* boff    = (int*)w; w += align_up((size_t)64 * 4);
    int* esrc    = (int*)w; w += align_up((size_t)N_EDGES * 4);

    // raise dynamic-LDS caps (one-time)
    static bool attr_done = false;
    if (!attr_done) {
        hipFuncSetAttribute((const void*)gemm_mfma,
                            hipFuncAttributeMaxDynamicSharedMemorySize,
                            GEMM_LDS_BYTES);              // 160 KB
        hipFuncSetAttribute((const void*)gemm_mlp2,
                            hipFuncAttributeMaxDynamicSharedMemorySize,
                            NBUF * BUF_U16 * 2);          // 144 KB
        attr_done = true;
    }

    // CSR build (cnt zeroing via async memset)
    hipMemsetAsync(cnt, 0, (size_t)N_NODES * 4, stream);
    count_deg<<<(N_EDGES + 255) / 256, 256, 0, stream>>>(ei, cnt);
    scan1<<<49, 1024, 0, stream>>>(cnt, partial, bsum);
    scan2<<<1, 64, 0, stream>>>(bsum, boff, 49);
    scan3<<<(N_NODES + 256) / 256, 256, 0, stream>>>(partial, boff, rowptr, cursor);
    fill_edges<<<(N_EDGES + 255) / 256, 256, 0, stream>>>(ei, cursor, esrc);

    // operand splits: x + 5 weight matrices in ONE launch
    {
        int total = (int)(NF + 5 * NW);
        split_all<<<(total + 255) / 256, 256, 0, stream>>>(
            x,   x_hi,  x_lo,
            W1l, w1l_h, w1l_l,
            W1r, w1r_h, w1r_l,
            W2l, w2l_h, w2l_l,
            W2r, w2r_h, w2r_l,
            Wm1, wm1_h, wm1_l);
    }

    dim3 ggrid((N_NODES + 255) / 256);        // 196 blocks: tail-free
    int agrid = (N_NODES + 3) / 4;            // one node per wave

    // Layer 1: aggregate bf16(x) hi-plane
    aggregate_bf16<<<agrid, 256, 0, stream>>>(x_hi, rowptr, esrc, mn_hi, mn_lo);
    gemm_mfma<<<ggrid, 512, GEMM_LDS_BYTES, stream>>>(mn_hi, mn_lo, x_hi, x_lo,
                                                      w1l_h, w1l_l, w1r_h, w1r_l,
                                                      b1, 512, h1_hi, h1_lo);
    // Layer 2: aggregate bf16(h1) hi-plane
    aggregate_bf16<<<agrid, 256, 0, stream>>>(h1_hi, rowptr, esrc, mn_hi, mn_lo);
    gemm_mfma<<<ggrid, 512, GEMM_LDS_BYTES, stream>>>(mn_hi, mn_lo, h1_hi, h1_lo,
                                                      w2l_h, w2l_l, w2r_h, w2r_l,
                                                      b2, 512, h2_hi, h2_lo);
    // MLP (K=256) fused with decoder + softmax
    gemm_mlp2<<<(N_NODES + 127) / 128, 512, NBUF * BUF_U16 * 2, stream>>>(
        h2_hi, h2_lo, wm1_h, wm1_l, bm1, Wm2, bm2, out);
}